// Round 8
// baseline (578.202 us; speedup 1.0000x reference)
//
#include <hip/hip_runtime.h>

#define LOG2E 1.4426950408889634f
#define LN2   0.6931471805599453f

namespace {
constexpr int B    = 64;
constexpr int T    = 2000;
constexpr int V    = 256;
constexpr int S    = 400;
constexpr int CHK  = 8;
constexpr int NCTP = 250;                 // chunks stored in G
constexpr int KP   = 408;                 // fragments per chunk (8*51)
constexpr size_t GELEM  = (size_t)B * NCTP * KP * 8;
constexpr size_t GBYTES = GELEM * 2;      // 104,448,000 B
constexpr size_t LAOFF  = GBYTES / 4;     // float offset of la in ws
constexpr size_t LGOFF  = LAOFF + 64 * 1024;
constexpr size_t REQBYTES = GBYTES + 2 * 64 * 1024 * 4;   // 104,972,288
constexpr int LSTR = 260;                 // gather LDS row stride
constexpr int NW7  = 7;                   // fallback params
constexpr int NCT7 = 250;
constexpr int BST7 = 12;
}

using h8 = __attribute__((ext_vector_type(8))) _Float16;

__device__ __forceinline__ float fexp2(float x){ return __builtin_amdgcn_exp2f(x); }
__device__ __forceinline__ float flog2(float x){ return __builtin_amdgcn_logf(x); }

// lane i <- lane i-1 (0 for lane 0)
__device__ __forceinline__ float wave_shr1(float x) {
  int v = __builtin_amdgcn_update_dpp(0, __builtin_bit_cast(int, x),
                                      0x138, 0xf, 0xf, true);
  return __builtin_bit_cast(float, v);
}
__device__ __forceinline__ int wave_shr1_i(int x) {
  return __builtin_amdgcn_update_dpp(0, x, 0x138, 0xf, 0xf, true);
}
// lane i <- lane i+1 (0 for lane 63)
__device__ __forceinline__ float wave_shl1(float x) {
  int v = __builtin_amdgcn_update_dpp(0, __builtin_bit_cast(int, x),
                                      0x130, 0xf, 0xf, true);
  return __builtin_bit_cast(float, v);
}
__device__ __forceinline__ int wave_shl1_i(int x) {
  return __builtin_amdgcn_update_dpp(0, x, 0x130, 0xf, 0xf, true);
}

// ---------------- gather (validated r15/r16) --------------------------------
// G layout: per (b,c), 408 fragments of 16B.  Fragment p = j*51 + l
// (j=0..7, l=0..50) holds fp16(exp(lp[1+8c+jj][ tgs[8l+j] ])) for jj=0..7,
// i.e. old row r = 8l+j.  k >= S -> blank (rows 400..407 live at l=50).
__global__ __launch_bounds__(512)
void ctc_gather_kernel(const float* __restrict__ logp,
                       const int* __restrict__ targets,
                       _Float16* __restrict__ G)
{
  const int tile = blockIdx.x;            // 32 tiles of 64 t-values
  const int b    = blockIdx.y;
  const int tid  = threadIdx.x;
  const int i0   = tile * 64;
  const float* lp = logp + (size_t)b * T * V;
  const int*   tg = targets + (size_t)b * S;

  __shared__ float ls[64 * LSTR];         // 65 KB
  __shared__ int   tgs[S];

  for (int f = tid; f < 64 * 64; f += 512) {
    const int row = f >> 6, c4 = f & 63;
    int t = i0 + 1 + row; if (t > T - 1) t = T - 1;
    float4 v = ((const float4*)(lp + (size_t)t * V))[c4];
    *(float4*)&ls[row * LSTR + c4 * 4] = v;
  }
  for (int k = tid; k < S; k += 512) tgs[k] = tg[k];
  __syncthreads();

  const int w    = tid >> 6;
  const int lane = tid & 63;
  _Float16* gb = G + (size_t)b * NCTP * KP * 8;

  // 8 chunks x 8 j-values; lanes 0..50 write contiguous 816B runs
  for (int it = w; it < 64; it += 8) {
    const int cc = it >> 3;
    const int j  = it & 7;
    const int c  = tile * 8 + cc;
    if (c >= NCTP) continue;
    if (lane > 50) continue;
    const int k = 8 * lane + j;           // old row index 0..407
    const int e = (k < S) ? tgs[k] : 1;   // k>=400: blank/pad
    h8 hv;
    #pragma unroll
    for (int jj = 0; jj < 8; ++jj)
      hv[jj] = (_Float16)fexp2(ls[(cc * 8 + jj) * LSTR + e] * LOG2E);
    *(h8*)(gb + ((size_t)c * KP + j * 51 + lane) * 8) = hv;
  }
}

// ---------------- fwd/bwd, TWO batch chains per wave ------------------------
// r16 post-mortem: with provably-resident data (depth-4 LDS ring, counted
// vmcnt) per-chunk time is still ~3000cy vs ~1200 issue -> the ~1700cy/chunk
// stall is NOT VMEM latency, NOT transactions, NOT prefetch depth.  Fit
// across 7 versions: cy/chunk ~= 1700 + 2.3*instrs; the constant is a
// latency-type stall (DPP forwarding / dep chains / wait quantization at
// 1 wave/SIMD, in-order issue).  Attack without identifying the mechanism:
// interleave TWO independent batch chains (b0,b1, same dir) in ONE wave --
// chain-1's independent instructions fill chain-0's stall slots.  Per-chunk
// -> max(1700, 2*issue), i.e. per-chain ~1700 vs ~2500.  Null result would
// falsify the latency theory (then revert to r11 4-wave + attack gather).
// (r17 bench died in container infra before running; resubmitted verbatim
// after audit: no spin loops, all accesses clamped, ~170 VGPR, bounded
// loops -- nothing that can hang a container.)
// 16-state/lane band + per-lane exponent E validated r12-r16 (absmax=0).
__global__ __launch_bounds__(64)
void ctc_fb_kernel(const float* __restrict__ logp,
                   const int* __restrict__ targets,
                   const int* __restrict__ input_len,
                   const int* __restrict__ target_len,
                   const _Float16* __restrict__ G,
                   float* __restrict__ la,
                   float* __restrict__ lg)
{
  const int b0   = 2 * blockIdx.x;
  const int b1   = b0 + 1;
  const int dir  = blockIdx.y;
  const int lane = threadIdx.x & 63;
  const float* __restrict__ lp0 = logp + (size_t)b0 * T * V;
  const float* __restrict__ lp1 = logp + (size_t)b1 * T * V;
  const int il0 = input_len[b0],  il1 = input_len[b1];
  const int tl0 = target_len[b0], tl1 = target_len[b1];
  const int m0  = il0 >> 1,       m1  = il1 >> 1;
  const int* tg0 = targets + (size_t)b0 * S;
  const int* tg1 = targets + (size_t)b1 * S;

  const _Float16* Gb0 = G + (size_t)b0 * NCTP * KP * 8;
  const _Float16* Gb1 = G + (size_t)b1 * NCTP * KP * 8;
  const int lclamp = (lane < 50) ? lane : 50;

  // dense chunk load: lane's 8 symbol frags (consecutive 16B) + blank
  auto loadch = [&](h8 (&buf)[9], const _Float16* Gbase, int c2) {
    if (c2 < 0) c2 = 0;
    if (c2 > NCTP - 1) c2 = NCTP - 1;
    const _Float16* src = Gbase + (size_t)c2 * (KP * 8);
    #pragma unroll
    for (int j = 0; j < 8; ++j)
      buf[j] = *(const h8*)(src + (size_t)(j * 51 + lclamp) * 8);
    buf[8] = *(const h8*)(src + (size_t)50 * 8);   // frag 50 = old row 400
  };

  auto renorm = [&](float (&a)[16], int &E, bool &alive) {
    float mx[8];
    #pragma unroll
    for (int q = 0; q < 8; ++q) mx[q] = fmaxf(a[2 * q], a[2 * q + 1]);
    #pragma unroll
    for (int q = 0; q < 4; ++q) mx[q] = fmaxf(mx[q], mx[q + 4]);
    const float m2 = fmaxf(fmaxf(mx[0], mx[1]), fmaxf(mx[2], mx[3]));
    int k = 0; (void)frexpf(m2, &k);
    #pragma unroll
    for (int i = 0; i < 16; ++i) a[i] = ldexpf(a[i], -k);
    E += k;
    alive = (m2 != 0.0f);
  };

  if (dir == 0) {
    // ======================= FORWARD (2 chains) =======================
    float skF0[8], skF1[8];
    #pragma unroll
    for (int j = 0; j < 8; ++j) {
      const int k  = 8 * lane + j;
      const int kc = k < S ? k : S - 1;
      const int km = (k - 1) < 0 ? 0 : ((k - 1) < S ? (k - 1) : S - 1);
      skF0[j] = (k > 0 && tg0[kc] != tg0[km]) ? 1.0f : 0.0f;
      skF1[j] = (k > 0 && tg1[kc] != tg1[km]) ? 1.0f : 0.0f;
    }

    float a0[16], a1[16];
    #pragma unroll
    for (int i = 0; i < 16; ++i) { a0[i] = 0.0f; a1[i] = 0.0f; }
    int  E0 = 0, E1 = 0;
    bool alive0 = (lane == 0), alive1 = (lane == 0);
    if (lane == 0) {
      a0[0] = fexp2(lp0[1] * LOG2E);  a0[1] = fexp2(lp0[tg0[0]] * LOG2E);
      a1[0] = fexp2(lp1[1] * LOG2E);  a1[1] = fexp2(lp1[tg1[0]] * LOG2E);
    }

    auto eexF = [&](int &E, bool alive) -> float {
      const int En = wave_shr1_i(E);
      if (!alive) E = En;
      int d = En - E; d = d > 126 ? 126 : (d < -126 ? -126 : d);
      return ldexpf(1.0f, d);
    };
    auto fstep = [&](float (&a)[16], const float (&sk)[8], h8 (&cur)[9],
                     float f, int i) {
      const float pbi = (float)cur[8][i];
      const float h = wave_shr1(a[15]) * f;     // state 16l-1 (0 @ lane0)
      #pragma unroll
      for (int j = 7; j >= 0; --j) {            // descending: pre-step reads
        const float psj = (float)cur[j][i];
        const float lo = j ? a[2 * j - 1] : h;
        a[2 * j + 1] = __builtin_fmaf(lo, sk[j],
                                      a[2 * j + 1] + a[2 * j]) * psj;
        a[2 * j]     = (a[2 * j] + lo) * pbi;
      }
    };

    h8 buf0[9], buf1[9];
    loadch(buf0, Gb0, 0); loadch(buf1, Gb1, 0);
    const int NCH0 = (m0 + 7) >> 3, NCH1 = (m1 + 7) >> 3;
    const int NCH = NCH0 > NCH1 ? NCH0 : NCH1;
    for (int n = 0; n < NCH; ++n) {
      const float f0 = eexF(E0, alive0);
      const float f1 = eexF(E1, alive1);
      #pragma unroll
      for (int i = 0; i < 8; ++i) {
        const int t = 1 + n * CHK + i;
        if (t <= m0) fstep(a0, skF0, buf0, f0, i);   // wave-uniform
        if (t <= m1) fstep(a1, skF1, buf1, f1, i);
      }
      loadch(buf0, Gb0, n + 1);                      // issue next chunk now
      loadch(buf1, Gb1, n + 1);
      renorm(a0, E0, alive0);
      renorm(a1, E1, alive1);
    }

    float* d0 = la + (size_t)b0 * 1024 + 16 * lane;
    float* d1 = la + (size_t)b1 * 1024 + 16 * lane;
    #pragma unroll
    for (int i = 0; i < 16; ++i) {
      d0[i] = flog2(a0[i]) + (float)E0;
      d1[i] = flog2(a1[i]) + (float)E1;
    }
  } else {
    // ======================= BACKWARD (2 chains) =======================
    float skB0[8], skB1[8];
    #pragma unroll
    for (int j = 0; j < 8; ++j) {
      const int k2  = 8 * lane + j + 1;
      const int k2c = k2 < S ? k2 : S - 1;
      const int k2m = (k2 - 1) < S ? (k2 - 1) : S - 1;
      skB0[j] = (tg0[k2c] != tg0[k2m]) ? 1.0f : 0.0f;
      skB1[j] = (tg1[k2c] != tg1[k2m]) ? 1.0f : 0.0f;
    }

    float g0[16], g1[16];
    const int s0 = 16 * lane;
    bool alive0 = false, alive1 = false;
    #pragma unroll
    for (int i = 0; i < 16; ++i) {
      const int s = s0 + i;
      g0[i] = (s == 2 * tl0 || s == 2 * tl0 - 1) ? 1.0f : 0.0f;
      g1[i] = (s == 2 * tl1 || s == 2 * tl1 - 1) ? 1.0f : 0.0f;
      alive0 = alive0 || (g0[i] != 0.0f);
      alive1 = alive1 || (g1[i] != 0.0f);
    }
    int E0 = 0, E1 = 0;

    auto eexB = [&](int &E, bool alive) -> float {
      const int En = wave_shl1_i(E);
      if (!alive) E = En;
      int d = En - E; d = d > 126 ? 126 : (d < -126 ? -126 : d);
      return ldexpf(1.0f, d);
    };
    auto bstep = [&](float (&g)[16], const float (&sk)[8], h8 (&cur)[9],
                     float f, int i) {
      const float pbi = (float)cur[8][i];
      float pg[16];
      #pragma unroll
      for (int q = 0; q < 8; ++q) {
        pg[2 * q]     = g[2 * q]     * pbi;
        pg[2 * q + 1] = g[2 * q + 1] * (float)cur[q][i];
      }
      const float h0 = wave_shl1(pg[0]) * f;    // state 16(l+1)   (0 @ 63)
      const float h1 = wave_shl1(pg[1]) * f;    // state 16(l+1)+1 (0 @ 63)
      #pragma unroll
      for (int q = 0; q < 8; ++q) {
        const float u1 = (q < 7) ? pg[2 * q + 2] : h0;
        const float u2 = (q < 7) ? pg[2 * q + 3] : h1;
        g[2 * q + 1] = __builtin_fmaf(u2, sk[q], pg[2 * q + 1] + u1);
        g[2 * q]     = pg[2 * q] + pg[2 * q + 1];
      }
    };

    const int c_hi0 = (il0 - 2) >> 3, c_lo0 = m0 >> 3;
    const int c_hi1 = (il1 - 2) >> 3, c_lo1 = m1 >> 3;
    const int span0 = c_hi0 - c_lo0, span1 = c_hi1 - c_lo1;
    const int SPAN = span0 > span1 ? span0 : span1;

    h8 buf0[9], buf1[9];
    loadch(buf0, Gb0, c_hi0); loadch(buf1, Gb1, c_hi1);
    for (int it = 0; it <= SPAN; ++it) {
      const int n0 = c_hi0 - it, n1 = c_hi1 - it;
      const float f0 = eexB(E0, alive0);
      const float f1 = eexB(E1, alive1);
      #pragma unroll
      for (int ii = 0; ii < 8; ++ii) {
        const int i = 7 - ii;                   // emission rows hi->lo
        const int r0 = 1 + n0 * CHK + i;
        const int r1 = 1 + n1 * CHK + i;
        if (r0 > m0 && r0 < il0) bstep(g0, skB0, buf0, f0, i);  // uniform
        if (r1 > m1 && r1 < il1) bstep(g1, skB1, buf1, f1, i);
      }
      loadch(buf0, Gb0, n0 - 1);                // issue next (clamped)
      loadch(buf1, Gb1, n1 - 1);
      renorm(g0, E0, alive0);
      renorm(g1, E1, alive1);
    }

    float* d0 = lg + (size_t)b0 * 1024 + 16 * lane;
    float* d1 = lg + (size_t)b1 * 1024 + 16 * lane;
    #pragma unroll
    for (int i = 0; i < 16; ++i) {
      d0[i] = flog2(g0[i]) + (float)E0;
      d1[i] = flog2(g1[i]) + (float)E1;
    }
  }
}

// ---------------- merge: loss_b = -ln sum_{s<Lb} 2^(la+lg), mean ------------
__global__ __launch_bounds__(64)
void ctc_merge_kernel(const float* __restrict__ la,
                      const float* __restrict__ lg,
                      const int* __restrict__ target_len,
                      float* __restrict__ out)
{
  const int b    = blockIdx.x;
  const int lane = threadIdx.x;
  const int tl = target_len[b];
  const int Lb = 2 * tl + 1;
  const float* A  = la + (size_t)b * 1024;
  const float* Gm = lg + (size_t)b * 1024;

  float vs[16];
  float vmax = -1e30f;
  #pragma unroll
  for (int r = 0; r < 16; ++r) {
    const int s = lane + 64 * r;
    float x = A[s] + Gm[s];
    x = (s < Lb) ? x : -1e30f;
    vs[r] = x;
    vmax = fmaxf(vmax, x);
  }
  #pragma unroll
  for (int o = 32; o > 0; o >>= 1) vmax = fmaxf(vmax, __shfl_xor(vmax, o, 64));
  float sum = 0.0f;
  #pragma unroll
  for (int r = 0; r < 16; ++r) sum += fexp2(vs[r] - vmax);
  #pragma unroll
  for (int o = 32; o > 0; o >>= 1) sum += __shfl_xor(sum, o, 64);
  if (lane == 0) {
    const float ll = (vmax + flog2(sum)) * LN2;
    float loss = -ll;
    if (!(loss < 1e29f)) loss = 0.0f;
    atomicAdd(out, loss / ((float)tl * (float)B));
  }
}

// ---------------- fallback: round-6 kernel (validated), if ws too small -----
__global__ __launch_bounds__(NW7 * 64)
void ctc_alpha7_kernel(const float* __restrict__ logp,
                       const int* __restrict__ targets,
                       const int* __restrict__ input_len,
                       const int* __restrict__ target_len,
                       float* __restrict__ out)
{
  const int b    = blockIdx.x;
  const int tid  = threadIdx.x;
  const int w    = tid >> 6;
  const int lane = tid & 63;
  const bool lane0 = (lane == 0);
  const float* __restrict__ lp = logp + (size_t)b * T * V;
  const int il = input_len[b];
  const int tl = target_len[b];
  const int Lb = 2 * tl + 1;

  __shared__ float bnd[NW7 - 1][NCT7 * BST7];
  __shared__ int   cnt[NW7 - 1];
  __shared__ float pblk[T];
  __shared__ float afin[NW7 * 64 * 2];

  if (tid < NW7 - 1) cnt[tid] = 0;

  const int* tg = targets + (size_t)b * S;
  const int k1 = (tid < S) ? tid : (S - 1);
  const int e1 = tg[k1];
  const float sk1 = (k1 == 0 || e1 != tg[k1 - 1]) ? 1.0f : 0.0f;

  for (int i = tid; i < T; i += NW7 * 64) {
    int t = (i + 1 < T) ? (i + 1) : (T - 1);
    pblk[i] = fexp2(lp[(size_t)t * V + 1] * LOG2E);
  }
  __syncthreads();

  const bool active = (w * 128) < Lb;
  if (active) {
    float a0 = 0.0f, a1 = 0.0f;
    int   E  = 0;
    if (tid == 0) { a0 = fexp2(lp[1] * LOG2E); a1 = fexp2(lp[e1] * LOG2E); }

    float tokL[CHK];
    #pragma unroll
    for (int i = 0; i < CHK; ++i) tokL[i] = lp[(size_t)(1 + i) * V + e1];

    const int NCH = (il - 1 + CHK - 1) / CHK;
    for (int c = 0; c < NCH; ++c) {
      const int t0 = 1 + c * CHK;
      float tokP[CHK];
      #pragma unroll
      for (int i = 0; i < CHK; ++i) tokP[i] = fexp2(tokL[i] * LOG2E);
      float nl[CHK];
      if (c + 1 < NCT7) {
        #pragma unroll
        for (int i = 0; i < CHK; ++i) {
          int tt = t0 + CHK + i; if (tt > T - 1) tt = T - 1;
          nl[i] = lp[(size_t)tt * V + e1];
        }
      }
      float pbk[CHK];
      {
        float4 q0 = *(const float4*)&pblk[c * CHK];
        float4 q1 = *(const float4*)&pblk[c * CHK + 4];
        pbk[0]=q0.x; pbk[1]=q0.y; pbk[2]=q0.z; pbk[3]=q0.w;
        pbk[4]=q1.x; pbk[5]=q1.y; pbk[6]=q1.z; pbk[7]=q1.w;
      }
      float bq[CHK];
      int Ep = 0;
      if (w > 0) {
        while (__hip_atomic_load(&cnt[w - 1], __ATOMIC_ACQUIRE,
                                 __HIP_MEMORY_SCOPE_WORKGROUP) < c + 1)
          __builtin_amdgcn_s_sleep(1);
        const float* src = &bnd[w - 1][c * BST7];
        float4 q0 = *(const float4*)(src);
        float4 q1 = *(const float4*)(src + 4);
        bq[0]=q0.x; bq[1]=q0.y; bq[2]=q0.z; bq[3]=q0.w;
        bq[4]=q1.x; bq[5]=q1.y; bq[6]=q1.z; bq[7]=q1.w;
        Ep = __float_as_int(src[8]);
      } else {
        #pragma unroll
        for (int i = 0; i < CHK; ++i) bq[i] = 0.0f;
      }
      const float mz  = fmaxf(a0, a1);
      const int   E1o = __shfl_up(E, 1);
      const int   E8  = __shfl_up(E, 8);
      const int   E9  = __shfl_up(E, 9);
      const float mz1 = __shfl_up(mz, 1);
      if (mz == 0.0f) E = (lane < 8) ? Ep : E8;
      int E1 = (mz1 == 0.0f) ? ((lane <= 8) ? Ep : E9) : E1o;
      if (lane0) E1 = (w == 0) ? E : Ep;
      int d = E1 - E; d = d > 126 ? 126 : (d < -126 ? -126 : d);
      const float f = ldexpf(1.0f, d);
      const float a1s = a1;
      float pub[CHK];
      #pragma unroll
      for (int i = 0; i < CHK; ++i) {
        const int t = t0 + i;
        if (t < il) {
          float hl = wave_shr1(a1);
          hl = lane0 ? bq[i] : hl;
          hl *= f;
          float s01 = a1 + a0;
          a1 = __builtin_fmaf(hl, sk1, s01) * tokP[i];
          a0 = (a0 + hl) * pbk[i];
        }
        pub[i] = a1;
      }
      if (w < NW7 - 1 && lane == 63) {
        float* dst = &bnd[w][c * BST7];
        dst[0] = a1s;
        #pragma unroll
        for (int i = 0; i < CHK - 1; ++i) dst[1 + i] = pub[i];
        dst[8] = __int_as_float(E);
        __hip_atomic_store(&cnt[w], c + 1, __ATOMIC_RELEASE,
                           __HIP_MEMORY_SCOPE_WORKGROUP);
      }
      {
        float m2 = fmaxf(a0, a1);
        int k = 0;
        (void)frexpf(m2, &k);
        a0 = ldexpf(a0, -k);
        a1 = ldexpf(a1, -k);
        E += k;
      }
      #pragma unroll
      for (int i = 0; i < CHK; ++i) tokL[i] = nl[i];
    }
    afin[2 * tid]     = flog2(a0) + (float)E;
    afin[2 * tid + 1] = flog2(a1) + (float)E;
  }
  __syncthreads();

  if (tid == 0) {
    const float x = afin[2 * tl];
    const float y = afin[2 * tl - 1];
    const float mm = fmaxf(x, y);
    const float ll = (mm + flog2(fexp2(x - mm) + fexp2(y - mm))) * LN2;
    float loss = -ll;
    if (!(loss < 1e29f)) loss = 0.0f;
    atomicAdd(out, loss / ((float)tl * (float)B));
  }
}

__global__ void ctc_zero_kernel(float* __restrict__ out) { out[0] = 0.0f; }

extern "C" void kernel_launch(void* const* d_in, const int* in_sizes, int n_in,
                              void* d_out, int out_size, void* d_ws, size_t ws_size,
                              hipStream_t stream) {
  const float* logp    = (const float*)d_in[0];
  const int*   targets = (const int*)d_in[1];
  const int*   il      = (const int*)d_in[2];
  const int*   tl      = (const int*)d_in[3];
  float* out = (float*)d_out;

  ctc_zero_kernel<<<1, 1, 0, stream>>>(out);
  if (ws_size >= REQBYTES) {
    _Float16* G  = (_Float16*)d_ws;
    float*    la = (float*)d_ws + LAOFF;
    float*    lg = (float*)d_ws + LGOFF;
    ctc_gather_kernel<<<dim3(32, B), 512, 0, stream>>>(logp, targets, G);
    ctc_fb_kernel<<<dim3(B / 2, 2), 64, 0, stream>>>(logp, targets, il, tl, G, la, lg);
    ctc_merge_kernel<<<B, 64, 0, stream>>>(la, lg, tl, out);
  } else {
    ctc_alpha7_kernel<<<B, NW7 * 64, 0, stream>>>(logp, targets, il, tl, out);
  }
}

// Round 9
// 339.032 us; speedup vs baseline: 1.7054x; 1.7054x over previous
//
#include <hip/hip_runtime.h>

#define LOG2E 1.4426950408889634f
#define LN2   0.6931471805599453f

namespace {
constexpr int B    = 64;
constexpr int T    = 2000;
constexpr int V    = 256;
constexpr int S    = 400;
constexpr int CHK  = 8;
constexpr int NCTP = 250;                 // chunks stored in G
constexpr int KP   = 408;                 // k rows per chunk (401 used, 8 pad)
constexpr size_t GELEM  = (size_t)B * NCTP * KP * 8;
constexpr size_t GBYTES = GELEM * 2;      // 104,448,000 B
constexpr size_t LAOFF  = GBYTES / 4;     // float offset of la in ws
constexpr size_t LGOFF  = LAOFF + 64 * 1024;
constexpr size_t REQBYTES = GBYTES + 2 * 64 * 1024 * 4;   // 104,972,288
constexpr int LSTR = 260;                 // gather LDS row stride
constexpr int NW7  = 7;                   // fallback params
constexpr int NCT7 = 250;
constexpr int BST7 = 12;
}

using h8 = __attribute__((ext_vector_type(8))) _Float16;

__device__ __forceinline__ float fexp2(float x){ return __builtin_amdgcn_exp2f(x); }
__device__ __forceinline__ float flog2(float x){ return __builtin_amdgcn_logf(x); }

// lane i <- lane i-1 (0 for lane 0)
__device__ __forceinline__ float wave_shr1(float x) {
  int v = __builtin_amdgcn_update_dpp(0, __builtin_bit_cast(int, x),
                                      0x138, 0xf, 0xf, true);
  return __builtin_bit_cast(float, v);
}
__device__ __forceinline__ int wave_shr1_i(int x) {
  return __builtin_amdgcn_update_dpp(0, x, 0x138, 0xf, 0xf, true);
}
// lane i <- lane i+1 (0 for lane 63)
__device__ __forceinline__ float wave_shl1(float x) {
  int v = __builtin_amdgcn_update_dpp(0, __builtin_bit_cast(int, x),
                                      0x130, 0xf, 0xf, true);
  return __builtin_bit_cast(float, v);
}
__device__ __forceinline__ int wave_shl1_i(int x) {
  return __builtin_amdgcn_update_dpp(0, x, 0x130, 0xf, 0xf, true);
}

// ---------------- gather (round-0 layout, validated) ------------------------
// G[b][c][k][j] = fp16(exp(lp[b][1+8c+j][tg[k]])), k=0..399; rows 400..407
// hold blank (col 1).  fb's per-chunk read: 512 consecutive 16B frags
// (one per thread) + a broadcast blank frag -- fully dense.
__global__ __launch_bounds__(512)
void ctc_gather_kernel(const float* __restrict__ logp,
                       const int* __restrict__ targets,
                       _Float16* __restrict__ G)
{
  const int tile = blockIdx.x;            // 32 tiles of 64 t-values
  const int b    = blockIdx.y;
  const int tid  = threadIdx.x;
  const int i0   = tile * 64;
  const float* lp = logp + (size_t)b * T * V;
  const int*   tg = targets + (size_t)b * S;

  __shared__ float ls[64 * LSTR];         // 65 KB
  __shared__ int   tgs[S];

  for (int f = tid; f < 64 * 64; f += 512) {
    const int row = f >> 6, c4 = f & 63;
    int t = i0 + 1 + row; if (t > T - 1) t = T - 1;
    float4 v = ((const float4*)(lp + (size_t)t * V))[c4];
    *(float4*)&ls[row * LSTR + c4 * 4] = v;
  }
  for (int k = tid; k < S; k += 512) tgs[k] = tg[k];
  __syncthreads();

  const int w    = tid >> 6;
  const int lane = tid & 63;
  _Float16* gb = G + (size_t)b * NCTP * KP * 8;

  // 7 k-blocks x 8 chunks; lane produces 8 j-values for one k (16B store)
  for (int it = w; it < 56; it += 8) {
    const int kb = it >> 3;
    const int cc = it & 7;
    const int c  = tile * 8 + cc;
    if (c >= NCTP) continue;
    const int k = kb * 64 + lane;
    if (k >= KP) continue;
    const int e = (k < S) ? tgs[k] : 1;   // rows 400..407: blank/pad
    h8 hv;
    #pragma unroll
    for (int j = 0; j < 8; ++j)
      hv[j] = (_Float16)fexp2(ls[(cc * 8 + j) * LSTR + e] * LOG2E);
    *(h8*)(gb + ((size_t)c * KP + k) * 8) = hv;
  }
}

// ---------------- fwd/bwd: 8-wave barrier pipeline, 2 states/lane -----------
// r18 post-mortem: doubling per-wave work doubled time (156->369) => fb is
// VALU-ISSUE-THROUGHPUT-bound, not latency-bound (all 8 prior schemes
// added instructions to a throughput-bound loop).  Lever: spread the
// per-chunk instruction stream across 8 SIMD-resident waves.  Structure =
// the VALIDATED alpha7 pipeline (2-state/lane recurrence, identical
// E-adoption with shfl_up(E,8/9), per-step boundary publish) ported to the
// meet-in-middle ranges, with __syncthreads + parity-double-buffered LDS
// slots replacing the spin/s_sleep protocol.  Wave w handles states
// 128w..128w+127; pipeline skew: wave w does chunk c at iter n=c+w (fwd) /
// n=(c_hi-c)+(7-w) (bwd).  Per-wave issue ~115 instrs/chunk (vs ~500
// single-wave); 2 waves/SIMD adds TLP over ds/L3 latencies.
__global__ __launch_bounds__(512)
void ctc_fb_kernel(const float* __restrict__ logp,
                   const int* __restrict__ targets,
                   const int* __restrict__ input_len,
                   const int* __restrict__ target_len,
                   const _Float16* __restrict__ G,
                   float* __restrict__ la,
                   float* __restrict__ lg)
{
  const int b    = blockIdx.x;
  const int dir  = blockIdx.y;
  const int tid  = threadIdx.x;
  const int w    = tid >> 6;
  const int lane = tid & 63;
  const bool lane0  = (lane == 0);
  const bool lane63 = (lane == 63);
  const float* __restrict__ lp = logp + (size_t)b * T * V;
  const int il = input_len[b];
  const int tl = target_len[b];
  const int m  = il >> 1;
  const int* tg = targets + (size_t)b * S;
  const _Float16* Gb = G + (size_t)b * NCTP * KP * 8;

  __shared__ float bnd[8][2][20];         // [wave][iter parity][payload]

  const int kfrag = (tid < KP) ? tid : (KP - 1);

  h8 As, Ak, Bs, Bk;                      // ping-pong chunk buffers

  if (dir == 0) {
    // ======================= FORWARD =======================
    const int k1 = (tid < S) ? tid : (S - 1);
    const float sk1 = (k1 == 0 || tg[k1] != tg[k1 - 1]) ? 1.0f : 0.0f;

    float a0 = 0.0f, a1 = 0.0f;
    int   E  = 0;
    if (tid == 0) {
      a0 = fexp2(lp[1] * LOG2E);          // t=0 blank
      a1 = fexp2(lp[tg[0]] * LOG2E);      // t=0 first symbol
    }

    // preload chunk 0 into BOTH buffers (every wave's first chunk is 0;
    // first active iteration parity differs per wave)
    As = *(const h8*)(Gb + (size_t)kfrag * 8);
    Ak = *(const h8*)(Gb + (size_t)400 * 8);
    Bs = As; Bk = Ak;

    const int NCH   = (m + 7) >> 3;
    const int NITER = NCH + 7;

    auto body = [&](int n, h8& curS, h8& curK, h8& nxtS, h8& nxtK) {
      __syncthreads();                    // uniform: all 512 threads
      const int c = n - w;
      if (c < 0 || c >= NCH) return;      // wave-uniform predicate
      float ps[8], pb[8];
      #pragma unroll
      for (int i = 0; i < 8; ++i) { ps[i] = (float)curS[i]; pb[i] = (float)curK[i]; }
      { // depth-1 prefetch (issued before compute; sched_barrier pins it)
        int c2 = c + 1; if (c2 > NCTP - 1) c2 = NCTP - 1;
        nxtS = *(const h8*)(Gb + ((size_t)c2 * KP + kfrag) * 8);
        nxtK = *(const h8*)(Gb + ((size_t)c2 * KP + 400) * 8);
        __builtin_amdgcn_sched_barrier(0);
      }
      float bq[8];
      int Ep = 0;
      if (w > 0) {                        // producer published at iter n-1
        const float* src = &bnd[w - 1][(n - 1) & 1][0];
        float4 q0 = *(const float4*)(src);
        float4 q1 = *(const float4*)(src + 4);
        bq[0]=q0.x; bq[1]=q0.y; bq[2]=q0.z; bq[3]=q0.w;
        bq[4]=q1.x; bq[5]=q1.y; bq[6]=q1.z; bq[7]=q1.w;
        Ep = __float_as_int(src[8]);
      } else {
        #pragma unroll
        for (int i = 0; i < 8; ++i) bq[i] = 0.0f;
      }
      // E exchange (alpha7-validated scheme)
      const float mz  = fmaxf(a0, a1);
      const int   E1o = __shfl_up(E, 1);
      const int   E8  = __shfl_up(E, 8);
      const int   E9  = __shfl_up(E, 9);
      const float mz1 = __shfl_up(mz, 1);
      if (mz == 0.0f) E = (lane < 8) ? Ep : E8;
      int E1 = (mz1 == 0.0f) ? ((lane <= 8) ? Ep : E9) : E1o;
      if (lane0) E1 = (w == 0) ? E : Ep;
      int d = E1 - E; d = d > 126 ? 126 : (d < -126 ? -126 : d);
      const float f = ldexpf(1.0f, d);

      const float a1s = a1;
      float pub[8];
      #pragma unroll
      for (int i = 0; i < 8; ++i) {
        const int t = 1 + c * CHK + i;
        if (t <= m) {                     // block-uniform predicate
          float hl = wave_shr1(a1);
          hl = lane0 ? bq[i] : hl;
          hl *= f;
          float s01 = a1 + a0;
          a1 = __builtin_fmaf(hl, sk1, s01) * ps[i];
          a0 = (a0 + hl) * pb[i];
        }
        pub[i] = a1;
      }
      if (w < 7 && lane63) {              // publish pre-renorm (E matches)
        float* dst = &bnd[w][n & 1][0];
        *(float4*)(dst)     = make_float4(a1s, pub[0], pub[1], pub[2]);
        *(float4*)(dst + 4) = make_float4(pub[3], pub[4], pub[5], pub[6]);
        dst[8] = __int_as_float(E);
      }
      { // renorm
        const float m2 = fmaxf(a0, a1);
        int kk = 0; (void)frexpf(m2, &kk);
        a0 = ldexpf(a0, -kk);
        a1 = ldexpf(a1, -kk);
        E += kk;
      }
    };

    for (int n = 0; n < NITER; n += 2) {
      body(n,     As, Ak, Bs, Bk);
      body(n + 1, Bs, Bk, As, Ak);        // overrun iteration is inert
    }

    float* dst = la + (size_t)b * 1024 + 2 * tid;
    dst[0] = flog2(a0) + (float)E;
    dst[1] = flog2(a1) + (float)E;
  } else {
    // ======================= BACKWARD =======================
    const int k2c = (tid + 1 < S) ? (tid + 1) : (S - 1);
    const int k2m = (tid < S) ? tid : (S - 1);
    const float skB = (tg[k2c] != tg[k2m]) ? 1.0f : 0.0f;

    const int s0 = 2 * tid;
    float g0 = (s0     == 2 * tl || s0     == 2 * tl - 1) ? 1.0f : 0.0f;
    float g1 = (s0 + 1 == 2 * tl || s0 + 1 == 2 * tl - 1) ? 1.0f : 0.0f;
    int   E  = 0;

    const int c_hi = (il - 2) >> 3;
    const int c_lo = m >> 3;
    const int NITER = (c_hi - c_lo) + 8;

    As = *(const h8*)(Gb + ((size_t)c_hi * KP + kfrag) * 8);
    Ak = *(const h8*)(Gb + ((size_t)c_hi * KP + 400) * 8);
    Bs = As; Bk = Ak;

    auto body = [&](int n, h8& curS, h8& curK, h8& nxtS, h8& nxtK) {
      __syncthreads();
      const int jn = n - (7 - w);
      const int c  = c_hi - jn;
      if (jn < 0 || c < c_lo) return;     // wave-uniform predicate
      float ps[8], pb[8];
      #pragma unroll
      for (int i = 0; i < 8; ++i) { ps[i] = (float)curS[i]; pb[i] = (float)curK[i]; }
      { // depth-1 prefetch (descending)
        int c2 = c - 1; if (c2 < 0) c2 = 0;
        nxtS = *(const h8*)(Gb + ((size_t)c2 * KP + kfrag) * 8);
        nxtK = *(const h8*)(Gb + ((size_t)c2 * KP + 400) * 8);
        __builtin_amdgcn_sched_barrier(0);
      }
      float bq0[8], bq1[8];
      int Ep = 0;
      if (w < 7) {                        // producer = wave w+1 at iter n-1
        const float* src = &bnd[w + 1][(n - 1) & 1][0];
        float4 q0 = *(const float4*)(src);
        float4 q1 = *(const float4*)(src + 4);
        float4 q2 = *(const float4*)(src + 8);
        float4 q3 = *(const float4*)(src + 12);
        bq0[0]=q0.x; bq0[1]=q0.y; bq0[2]=q0.z; bq0[3]=q0.w;
        bq0[4]=q1.x; bq0[5]=q1.y; bq0[6]=q1.z; bq0[7]=q1.w;
        bq1[0]=q2.x; bq1[1]=q2.y; bq1[2]=q2.z; bq1[3]=q2.w;
        bq1[4]=q3.x; bq1[5]=q3.y; bq1[6]=q3.z; bq1[7]=q3.w;
        Ep = __float_as_int(src[16]);
      } else {
        #pragma unroll
        for (int i = 0; i < 8; ++i) { bq0[i] = 0.0f; bq1[i] = 0.0f; }
      }
      // E exchange (mirror of forward scheme)
      const float mz  = fmaxf(g0, g1);
      const int   E1o = wave_shl1_i(E);
      const int   E8  = __shfl_down(E, 8);
      const int   E9  = __shfl_down(E, 9);
      const float mzN = wave_shl1(mz);
      if (mz == 0.0f) E = (lane >= 56) ? Ep : E8;
      int E1 = (mzN == 0.0f) ? ((lane >= 55) ? Ep : E9) : E1o;
      if (lane63) E1 = (w == 7) ? E : Ep;
      int d = E1 - E; d = d > 126 ? 126 : (d < -126 ? -126 : d);
      const float f = ldexpf(1.0f, d);

      float pub0[8], pub1[8];
      #pragma unroll
      for (int i = 0; i < 8; ++i) { pub0[i] = 0.0f; pub1[i] = 0.0f; }
      #pragma unroll
      for (int ii = 0; ii < 8; ++ii) {
        const int i = 7 - ii;             // emission rows hi->lo
        const int row = 1 + c * CHK + i;
        if (row > m && row < il) {        // block-uniform predicate
          float pg0 = g0 * pb[i];
          float pg1 = g1 * ps[i];
          float h0 = wave_shl1(pg0);      // state 2(tid+1)
          float h1 = wave_shl1(pg1);      // state 2(tid+1)+1
          h0 = lane63 ? bq0[i] : h0;
          h1 = lane63 ? bq1[i] : h1;
          h0 *= f;
          h1 *= f;
          pub0[i] = pg0; pub1[i] = pg1;
          g1 = __builtin_fmaf(h1, skB, pg1 + h0);
          g0 = pg0 + pg1;
        }
      }
      if (w > 0 && lane0) {               // publish pre-renorm
        float* dst = &bnd[w][n & 1][0];
        *(float4*)(dst)      = make_float4(pub0[0], pub0[1], pub0[2], pub0[3]);
        *(float4*)(dst + 4)  = make_float4(pub0[4], pub0[5], pub0[6], pub0[7]);
        *(float4*)(dst + 8)  = make_float4(pub1[0], pub1[1], pub1[2], pub1[3]);
        *(float4*)(dst + 12) = make_float4(pub1[4], pub1[5], pub1[6], pub1[7]);
        dst[16] = __int_as_float(E);
      }
      {
        const float m2 = fmaxf(g0, g1);
        int kk = 0; (void)frexpf(m2, &kk);
        g0 = ldexpf(g0, -kk);
        g1 = ldexpf(g1, -kk);
        E += kk;
      }
    };

    for (int n = 0; n < NITER; n += 2) {
      body(n,     As, Ak, Bs, Bk);
      body(n + 1, Bs, Bk, As, Ak);
    }

    float* dst = lg + (size_t)b * 1024 + 2 * tid;
    dst[0] = flog2(g0) + (float)E;
    dst[1] = flog2(g1) + (float)E;
  }
}

// ---------------- merge: loss_b = -ln sum_{s<Lb} 2^(la+lg), mean ------------
__global__ __launch_bounds__(64)
void ctc_merge_kernel(const float* __restrict__ la,
                      const float* __restrict__ lg,
                      const int* __restrict__ target_len,
                      float* __restrict__ out)
{
  const int b    = blockIdx.x;
  const int lane = threadIdx.x;
  const int tl = target_len[b];
  const int Lb = 2 * tl + 1;
  const float* A  = la + (size_t)b * 1024;
  const float* Gm = lg + (size_t)b * 1024;

  float vs[16];
  float vmax = -1e30f;
  #pragma unroll
  for (int r = 0; r < 16; ++r) {
    const int s = lane + 64 * r;
    float x = A[s] + Gm[s];
    x = (s < Lb) ? x : -1e30f;
    vs[r] = x;
    vmax = fmaxf(vmax, x);
  }
  #pragma unroll
  for (int o = 32; o > 0; o >>= 1) vmax = fmaxf(vmax, __shfl_xor(vmax, o, 64));
  float sum = 0.0f;
  #pragma unroll
  for (int r = 0; r < 16; ++r) sum += fexp2(vs[r] - vmax);
  #pragma unroll
  for (int o = 32; o > 0; o >>= 1) sum += __shfl_xor(sum, o, 64);
  if (lane == 0) {
    const float ll = (vmax + flog2(sum)) * LN2;
    float loss = -ll;
    if (!(loss < 1e29f)) loss = 0.0f;
    atomicAdd(out, loss / ((float)tl * (float)B));
  }
}

// ---------------- fallback: round-6 kernel (validated), if ws too small -----
__global__ __launch_bounds__(NW7 * 64)
void ctc_alpha7_kernel(const float* __restrict__ logp,
                       const int* __restrict__ targets,
                       const int* __restrict__ input_len,
                       const int* __restrict__ target_len,
                       float* __restrict__ out)
{
  const int b    = blockIdx.x;
  const int tid  = threadIdx.x;
  const int w    = tid >> 6;
  const int lane = tid & 63;
  const bool lane0 = (lane == 0);
  const float* __restrict__ lp = logp + (size_t)b * T * V;
  const int il = input_len[b];
  const int tl = target_len[b];
  const int Lb = 2 * tl + 1;

  __shared__ float bnd[NW7 - 1][NCT7 * BST7];
  __shared__ int   cnt[NW7 - 1];
  __shared__ float pblk[T];
  __shared__ float afin[NW7 * 64 * 2];

  if (tid < NW7 - 1) cnt[tid] = 0;

  const int* tg = targets + (size_t)b * S;
  const int k1 = (tid < S) ? tid : (S - 1);
  const int e1 = tg[k1];
  const float sk1 = (k1 == 0 || e1 != tg[k1 - 1]) ? 1.0f : 0.0f;

  for (int i = tid; i < T; i += NW7 * 64) {
    int t = (i + 1 < T) ? (i + 1) : (T - 1);
    pblk[i] = fexp2(lp[(size_t)t * V + 1] * LOG2E);
  }
  __syncthreads();

  const bool active = (w * 128) < Lb;
  if (active) {
    float a0 = 0.0f, a1 = 0.0f;
    int   E  = 0;
    if (tid == 0) { a0 = fexp2(lp[1] * LOG2E); a1 = fexp2(lp[e1] * LOG2E); }

    float tokL[CHK];
    #pragma unroll
    for (int i = 0; i < CHK; ++i) tokL[i] = lp[(size_t)(1 + i) * V + e1];

    const int NCH = (il - 1 + CHK - 1) / CHK;
    for (int c = 0; c < NCH; ++c) {
      const int t0 = 1 + c * CHK;
      float tokP[CHK];
      #pragma unroll
      for (int i = 0; i < CHK; ++i) tokP[i] = fexp2(tokL[i] * LOG2E);
      float nl[CHK];
      if (c + 1 < NCT7) {
        #pragma unroll
        for (int i = 0; i < CHK; ++i) {
          int tt = t0 + CHK + i; if (tt > T - 1) tt = T - 1;
          nl[i] = lp[(size_t)tt * V + e1];
        }
      }
      float pbk[CHK];
      {
        float4 q0 = *(const float4*)&pblk[c * CHK];
        float4 q1 = *(const float4*)&pblk[c * CHK + 4];
        pbk[0]=q0.x; pbk[1]=q0.y; pbk[2]=q0.z; pbk[3]=q0.w;
        pbk[4]=q1.x; pbk[5]=q1.y; pbk[6]=q1.z; pbk[7]=q1.w;
      }
      float bq[CHK];
      int Ep = 0;
      if (w > 0) {
        while (__hip_atomic_load(&cnt[w - 1], __ATOMIC_ACQUIRE,
                                 __HIP_MEMORY_SCOPE_WORKGROUP) < c + 1)
          __builtin_amdgcn_s_sleep(1);
        const float* src = &bnd[w - 1][c * BST7];
        float4 q0 = *(const float4*)(src);
        float4 q1 = *(const float4*)(src + 4);
        bq[0]=q0.x; bq[1]=q0.y; bq[2]=q0.z; bq[3]=q0.w;
        bq[4]=q1.x; bq[5]=q1.y; bq[6]=q1.z; bq[7]=q1.w;
        Ep = __float_as_int(src[8]);
      } else {
        #pragma unroll
        for (int i = 0; i < CHK; ++i) bq[i] = 0.0f;
      }
      const float mz  = fmaxf(a0, a1);
      const int   E1o = __shfl_up(E, 1);
      const int   E8  = __shfl_up(E, 8);
      const int   E9  = __shfl_up(E, 9);
      const float mz1 = __shfl_up(mz, 1);
      if (mz == 0.0f) E = (lane < 8) ? Ep : E8;
      int E1 = (mz1 == 0.0f) ? ((lane <= 8) ? Ep : E9) : E1o;
      if (lane0) E1 = (w == 0) ? E : Ep;
      int d = E1 - E; d = d > 126 ? 126 : (d < -126 ? -126 : d);
      const float f = ldexpf(1.0f, d);
      const float a1s = a1;
      float pub[CHK];
      #pragma unroll
      for (int i = 0; i < CHK; ++i) {
        const int t = t0 + i;
        if (t < il) {
          float hl = wave_shr1(a1);
          hl = lane0 ? bq[i] : hl;
          hl *= f;
          float s01 = a1 + a0;
          a1 = __builtin_fmaf(hl, sk1, s01) * tokP[i];
          a0 = (a0 + hl) * pbk[i];
        }
        pub[i] = a1;
      }
      if (w < NW7 - 1 && lane == 63) {
        float* dst = &bnd[w][c * BST7];
        dst[0] = a1s;
        #pragma unroll
        for (int i = 0; i < CHK - 1; ++i) dst[1 + i] = pub[i];
        dst[8] = __int_as_float(E);
        __hip_atomic_store(&cnt[w], c + 1, __ATOMIC_RELEASE,
                           __HIP_MEMORY_SCOPE_WORKGROUP);
      }
      {
        float m2 = fmaxf(a0, a1);
        int k = 0;
        (void)frexpf(m2, &k);
        a0 = ldexpf(a0, -k);
        a1 = ldexpf(a1, -k);
        E += k;
      }
      #pragma unroll
      for (int i = 0; i < CHK; ++i) tokL[i] = nl[i];
    }
    afin[2 * tid]     = flog2(a0) + (float)E;
    afin[2 * tid + 1] = flog2(a1) + (float)E;
  }
  __syncthreads();

  if (tid == 0) {
    const float x = afin[2 * tl];
    const float y = afin[2 * tl - 1];
    const float mm = fmaxf(x, y);
    const float ll = (mm + flog2(fexp2(x - mm) + fexp2(y - mm))) * LN2;
    float loss = -ll;
    if (!(loss < 1e29f)) loss = 0.0f;
    atomicAdd(out, loss / ((float)tl * (float)B));
  }
}

__global__ void ctc_zero_kernel(float* __restrict__ out) { out[0] = 0.0f; }

extern "C" void kernel_launch(void* const* d_in, const int* in_sizes, int n_in,
                              void* d_out, int out_size, void* d_ws, size_t ws_size,
                              hipStream_t stream) {
  const float* logp    = (const float*)d_in[0];
  const int*   targets = (const int*)d_in[1];
  const int*   il      = (const int*)d_in[2];
  const int*   tl      = (const int*)d_in[3];
  float* out = (float*)d_out;

  ctc_zero_kernel<<<1, 1, 0, stream>>>(out);
  if (ws_size >= REQBYTES) {
    _Float16* G  = (_Float16*)d_ws;
    float*    la = (float*)d_ws + LAOFF;
    float*    lg = (float*)d_ws + LGOFF;
    ctc_gather_kernel<<<dim3(32, B), 512, 0, stream>>>(logp, targets, G);
    ctc_fb_kernel<<<dim3(B, 2), 512, 0, stream>>>(logp, targets, il, tl, G, la, lg);
    ctc_merge_kernel<<<B, 64, 0, stream>>>(la, lg, tl, out);
  } else {
    ctc_alpha7_kernel<<<B, NW7 * 64, 0, stream>>>(logp, targets, il, tl, out);
  }
}